// Round 3
// baseline (578.390 us; speedup 1.0000x reference)
//
#include <hip/hip_runtime.h>
#include <math.h>

#define N 8192
#define IN_F 512
#define OUTF 64
#define TI 16
#define JT 256               // j-cols per tile
#define NTILE (N / JT)       // 32 phases
#define PS 264               // P_lds row stride (f16)

typedef _Float16 f16x8 __attribute__((ext_vector_type(8)));
typedef float f32x4 __attribute__((ext_vector_type(4)));

// workspace layout (floats) — ~1.1 MB
#define OFF_HT   0u          // hT: 64x8192 f16 = 262144 float-slots
#define OFF_S    262144u     // s2 = |W_ei| * (h@a1)
#define OFF_T    270336u     // t2 = |W_ei| * (h@a2)
#define OFF_TMAX 278528u     // 16

#define SB0() __builtin_amdgcn_sched_barrier(0)
#define SYNC()                                           \
  SB0();                                                 \
  asm volatile("s_waitcnt lgkmcnt(0)" ::: "memory");     \
  SB0();                                                 \
  __builtin_amdgcn_s_barrier();                          \
  SB0();

__device__ __forceinline__ unsigned enc_f32(float f) {
  unsigned b = __float_as_uint(f);
  return b ^ ((unsigned)((int)b >> 31) | 0x80000000u);
}

// ---------------------------------------------------------------------------
// K1: hT[f][j] = (f16)(input@W)[j][f]; s2 = aei*(h@a1); t2 = aei*(h@a2).
// aei = |W_ei| folded here so k_attn's per-element path saves a multiply:
// aei*lrelu(s+t) == fmax(y, 0.2y) with y = s2+t2 (aei >= 0, lrelu pos-homog).
// ---------------------------------------------------------------------------
__global__ __launch_bounds__(64) void k_precompute(
    const float* __restrict__ input, const float* __restrict__ W,
    const float* __restrict__ a, const float* __restrict__ W_ei,
    _Float16* __restrict__ hT, float* __restrict__ s2,
    float* __restrict__ t2) {
  const int lane = threadIdx.x;
  const int i0 = blockIdx.x * 4;
  const float aei = fabsf(W_ei[0]);

  float acc[4] = {0.f, 0.f, 0.f, 0.f};
  for (int c = 0; c < IN_F; c += 4) {
    const float w0 = W[(c + 0) * OUTF + lane];
    const float w1 = W[(c + 1) * OUTF + lane];
    const float w2 = W[(c + 2) * OUTF + lane];
    const float w3 = W[(c + 3) * OUTF + lane];
    #pragma unroll
    for (int r = 0; r < 4; r++) {
      const float4 iv = *(const float4*)(input + (size_t)(i0 + r) * IN_F + c);
      acc[r] += iv.x * w0 + iv.y * w1 + iv.z * w2 + iv.w * w3;
    }
  }

  union { _Float16 f[4]; uint2 u; } pk;
  #pragma unroll
  for (int r = 0; r < 4; r++) pk.f[r] = (_Float16)acc[r];
  *(uint2*)(hT + (size_t)lane * N + i0) = pk.u;

  const float a1v = a[lane];
  const float a2v = a[OUTF + lane];
  #pragma unroll
  for (int r = 0; r < 4; r++) {
    float sv = acc[r] * a1v;
    float tv = acc[r] * a2v;
    #pragma unroll
    for (int off = 1; off < 64; off <<= 1) {
      sv += __shfl_xor(sv, off);
      tv += __shfl_xor(tv, off);
    }
    if (lane == 0) {
      s2[i0 + r] = aei * sv;
      t2[i0 + r] = aei * tv;
    }
  }
}

// ---------------------------------------------------------------------------
// K1.5: max(t2) via atomicMax on monotone-encoded uint (memset-0 init).
// ---------------------------------------------------------------------------
__global__ __launch_bounds__(512) void k_tmax(const float* __restrict__ t,
                                              unsigned* __restrict__ tmax) {
  __shared__ float red[8];
  const int tid = threadIdx.x;
  float m = t[blockIdx.x * 512 + tid];
  #pragma unroll
  for (int off = 1; off < 64; off <<= 1) m = fmaxf(m, __shfl_xor(m, off));
  if ((tid & 63) == 0) red[tid >> 6] = m;
  __syncthreads();
  if (tid == 0) {
    #pragma unroll
    for (int w = 1; w < 8; w++) m = fmaxf(m, red[w]);
    atomicMax(tmax, enc_f32(m));
  }
}

// ---------------------------------------------------------------------------
// K2 v4: reg-direct streams + tiny f16 P-tile through LDS.
//
// R0/R2 showed a ~2.7 TB/s cap common to BOTH DMA-staging schedules (drain
// and counted-vmcnt) -> the cap follows the global_load_lds + 1-WG/CU +
// 8-wave-lockstep structure, not the address pattern. adj/adj_ad need no
// cross-lane exchange pre-exp (elementwise), so stream them with plain
// lane-contiguous dwordx4 (the m13 6.3 TB/s path): each wave owns 2 rows,
// lane (h,cw) reads row 2w+h cols cw*4+{0,128}. Only the post-exp f16
// P-tile (8 KB/phase) goes through LDS (double-buffered) to bridge to the
// MFMA A-fragment layout. LDS 133KB -> 33KB => 2 WGs/CU (16 waves, fully
// decoupled). SYNC = lgkmcnt(0) + raw s_barrier (NO vmcnt: the tile-k+1
// prefetch rides across, T4). sched_barrier(0) pins short-latency hT/t/fa
// issues BEFORE the prefetch so their waits leave it in flight.
// ---------------------------------------------------------------------------
__global__ __launch_bounds__(512, 4) void k_attn(
    const _Float16* __restrict__ hT, const float* __restrict__ s2,
    const float* __restrict__ t2, const unsigned* __restrict__ tmaxp,
    const float* __restrict__ W_si, const float* __restrict__ W_ei,
    const float* __restrict__ adj_ad, const int* __restrict__ adj,
    float* __restrict__ out) {
  __shared__ __align__(16) float smem[8224];   // 32896 B
  _Float16* P = (_Float16*)smem;               // [2][16][PS] f16 = 16896 B

  const int tid = threadIdx.x;
  const int w = tid >> 6;          // wave 0..7
  const int lane = tid & 63;
  const int q = lane >> 4;
  const int m = lane & 15;
  const int h2 = lane >> 5;        // half-wave -> row parity
  const int cw = lane & 31;        // col-lane within half
  const int i0 = blockIdx.x * TI;

  const float asi = fabsf(W_si[0]);
  (void)W_ei;                      // folded into s2/t2 at precompute
  const unsigned te = *tmaxp;
  const float tm2 = __uint_as_float((te & 0x80000000u) ? (te ^ 0x80000000u) : ~te);

  const int myrow = 2 * w + h2;
  const float s2r = s2[i0 + myrow];
  const float ym = s2r + tm2;
  const float MrB = fmaxf(ym, 0.2f * ym) + asi;   // row upper bound on e

  float S = 0.f;
  f32x4 acc[4];
  #pragma unroll
  for (int nb = 0; nb < 4; nb++) acc[nb] = (f32x4){0.f, 0.f, 0.f, 0.f};

  const size_t gRow = (size_t)(i0 + myrow) * N;
  const int c0 = cw * 4;           // cols c0 and c0+128 within tile

  struct PF { float4 a0, a1; int4 k0, k1; };

  auto LOADT = [&](int kt) -> PF {
    const size_t b = gRow + (size_t)kt * JT + c0;
    PF p;
    p.a0 = *(const float4*)(adj_ad + b);
    p.a1 = *(const float4*)(adj_ad + b + 128);
    p.k0 = *(const int4*)(adj + b);
    p.k1 = *(const int4*)(adj + b + 128);
    return p;
  };

  auto EXPW = [&](int kt, const PF& p, const float4& tva, const float4& tvb) {
    const float ad[8] = {p.a0.x, p.a0.y, p.a0.z, p.a0.w,
                         p.a1.x, p.a1.y, p.a1.z, p.a1.w};
    const int mk[8] = {p.k0.x, p.k0.y, p.k0.z, p.k0.w,
                       p.k1.x, p.k1.y, p.k1.z, p.k1.w};
    const float tv[8] = {tva.x, tva.y, tva.z, tva.w,
                         tvb.x, tvb.y, tvb.z, tvb.w};
    union { _Float16 hh[8]; uint2 u[2]; } pk;
    #pragma unroll
    for (int e = 0; e < 8; e++) {
      const float y = s2r + tv[e];
      const float lr = fmaxf(y, 0.2f * y);
      const float arg = fmaf(asi, ad[e], lr - MrB);   // <= 0 always
      const float pv = __expf(arg) * (float)mk[e];    // mk in {0,1}
      S += pv;
      pk.hh[e] = (_Float16)pv;
    }
    _Float16* dst = P + (kt & 1) * (16 * PS) + myrow * PS;
    *(uint2*)(dst + c0) = pk.u[0];
    *(uint2*)(dst + c0 + 128) = pk.u[1];
  };

  #define MLOAD(kt, FB, FA)                                                   \
    {                                                                         \
      const int cb_ = (kt) * JT + w * 32 + q * 8;                             \
      _Pragma("unroll") for (int nb = 0; nb < 4; nb++)                        \
          FB[nb] = *(const f16x8*)(hT + (size_t)(nb * 16 + m) * N + cb_);     \
      FA = *(const f16x8*)(P + ((kt) & 1) * (16 * PS) + m * PS + w * 32 +     \
                           q * 8);                                            \
    }

  #define MSTEP(FB, FA)                                                       \
    {                                                                         \
      _Pragma("unroll") for (int nb = 0; nb < 4; nb++)                        \
          acc[nb] = __builtin_amdgcn_mfma_f32_16x16x32_f16(FA, FB[nb],        \
                                                           acc[nb], 0, 0, 0);\
    }

  PF pA = LOADT(0);
  PF pB;

  #pragma unroll 1
  for (int k = 0; k < NTILE; k += 2) {
    // ---- sub-phase A: MFMA(k-1); exp(k) from pA; prefetch k+1 -> pB ----
    {
      const float4 tva = *(const float4*)(t2 + k * JT + c0);
      const float4 tvb = *(const float4*)(t2 + k * JT + c0 + 128);
      f16x8 fb[4], fa;
      if (k >= 1) MLOAD(k - 1, fb, fa);
      SB0();
      pB = LOADT(k + 1);             // HBM prefetch, stays in flight
      SB0();
      if (k >= 1) MSTEP(fb, fa);     // fb wait leaves newest-4 (pB) in flight
      EXPW(k, pA, tva, tvb);         // pA is oldest -> already drained
      SYNC();
    }
    // ---- sub-phase B: MFMA(k); exp(k+1) from pB; prefetch k+2 -> pA ----
    {
      const float4 tva = *(const float4*)(t2 + (k + 1) * JT + c0);
      const float4 tvb = *(const float4*)(t2 + (k + 1) * JT + c0 + 128);
      f16x8 fb[4], fa;
      MLOAD(k, fb, fa);
      SB0();
      if (k + 2 < NTILE) pA = LOADT(k + 2);
      SB0();
      MSTEP(fb, fa);
      EXPW(k + 1, pB, tva, tvb);
      SYNC();
    }
  }

  // trailing MFMA for tile NTILE-1
  {
    f16x8 fb[4], fa;
    MLOAD(NTILE - 1, fb, fa);
    MSTEP(fb, fa);
  }

  // row-sum S within half-wave (32 lanes cover one row)
  #pragma unroll
  for (int off = 1; off < 32; off <<= 1) S += __shfl_xor(S, off);

  SYNC();   // all P reads complete before smem is repurposed

  // ---- epilogue: cross-wave reduce in LDS ----
  if ((lane & 31) == 0) smem[8192 + myrow] = S;
  #pragma unroll
  for (int nb = 0; nb < 4; nb++) {
    #pragma unroll
    for (int reg = 0; reg < 4; reg++) {
      smem[w * 1024 + (q * 4 + reg) * 64 + nb * 16 + m] = acc[nb][reg];
    }
  }
  __syncthreads();

  #pragma unroll
  for (int ii = 0; ii < 2; ii++) {
    const int e = tid + 512 * ii;
    const int r = e >> 6;
    const int f = e & 63;
    float num = 0.f;
    #pragma unroll
    for (int ww = 0; ww < 8; ww++) num += smem[ww * 1024 + r * 64 + f];
    const float den = smem[8192 + r];
    const float x = num / den;
    out[(size_t)(i0 + r) * OUTF + f] = x > 0.f ? x : expm1f(x);
  }
}

// ---------------------------------------------------------------------------
extern "C" void kernel_launch(void* const* d_in, const int* in_sizes, int n_in,
                              void* d_out, int out_size, void* d_ws, size_t ws_size,
                              hipStream_t stream) {
  const float* input  = (const float*)d_in[0];
  const float* W      = (const float*)d_in[1];
  const float* a      = (const float*)d_in[2];
  const float* W_si   = (const float*)d_in[3];
  const float* W_ei   = (const float*)d_in[4];
  const float* adj_ad = (const float*)d_in[5];
  const int*   adj    = (const int*)d_in[6];
  float* out = (float*)d_out;
  float* ws  = (float*)d_ws;

  _Float16* hT   = (_Float16*)(ws + OFF_HT);
  float* s2      = ws + OFF_S;
  float* t2      = ws + OFF_T;
  unsigned* tmax = (unsigned*)(ws + OFF_TMAX);

  hipMemsetAsync(tmax, 0, 4, stream);
  k_precompute<<<N / 4, 64, 0, stream>>>(input, W, a, W_ei, hT, s2, t2);
  k_tmax<<<N / 512, 512, 0, stream>>>(t2, tmax);
  k_attn<<<N / TI, 512, 0, stream>>>(hT, s2, t2, tmax, W_si, W_ei,
                                     adj_ad, adj, out);
}